// Round 1
// baseline (83.881 us; speedup 1.0000x reference)
//
#include <hip/hip_runtime.h>

#define TPB 256

// Kernel A: compute soft permutations P1, P2 (each 10x10) into d_ws.
// P layout: P[0..99] = soft_perm(W1) row-major, P[100..199] = soft_perm(W2).
__global__ void softperm_kernel(const float* __restrict__ W1,
                                const float* __restrict__ W2,
                                float* __restrict__ P) {
    int t = threadIdx.x;
    if (t >= 20) return;
    const float* W = (t < 10) ? W1 : W2;
    int r = (t < 10) ? t : (t - 10);
    float w[10];
    float lo = 1e30f, hi = -1e30f;
#pragma unroll
    for (int j = 0; j < 10; ++j) {
        w[j] = W[r * 10 + j];
        lo = fminf(lo, w[j]);
        hi = fmaxf(hi, w[j]);
    }
    float inv = 1.0f / (hi - lo + 1e-8f);
    float s = 0.0f;
#pragma unroll
    for (int j = 0; j < 10; ++j) { w[j] = (w[j] - lo) * inv; s += w[j]; }
    float invs = 1.0f / (s + 1e-8f);
#pragma unroll
    for (int j = 0; j < 10; ++j) P[t * 10 + j] = w[j] * invs;
}

// Kernel B: main. One thread per row.
//  - Stage 256 rows of p1/p2 into LDS via coalesced float4 loads.
//  - l1 = P1 @ p1row, l2 = P2 @ p2row with P via scalar loads (uniform addr).
//  - log(1-min(a,b)) == max(log(1-a), log(1-b))  -> only 20 logs/row.
//  - Stage 19 outputs/row in LDS, coalesced float4 store.
__global__ __launch_bounds__(TPB) void bacon_main(
    const float* __restrict__ p1, const float* __restrict__ p2,
    const float* __restrict__ P, float* __restrict__ out, int nrows) {
    // 2*256*10 floats for input staging = 20480 B; reused for output
    // staging (256*19 = 4864 floats <= 5120).
    __shared__ __align__(16) float sIn[2 * TPB * 10];

    const int tid = threadIdx.x;
    const int rowBase = blockIdx.x * TPB;
    int rowsHere = nrows - rowBase;
    if (rowsHere > TPB) rowsHere = TPB;

    // ---- stage inputs (coalesced) ----
    {
        const int nflt = rowsHere * 10;
        const int nvec = nflt >> 2;
        const float4* g1 = (const float4*)(p1 + (size_t)rowBase * 10);
        const float4* g2 = (const float4*)(p2 + (size_t)rowBase * 10);
        float4* s1 = (float4*)sIn;
        float4* s2 = (float4*)(sIn + TPB * 10);
        for (int e = tid; e < nvec; e += TPB) {
            s1[e] = g1[e];
            s2[e] = g2[e];
        }
        for (int e = (nvec << 2) + tid; e < nflt; e += TPB) {
            sIn[e] = p1[(size_t)rowBase * 10 + e];
            sIn[TPB * 10 + e] = p2[(size_t)rowBase * 10 + e];
        }
    }
    __syncthreads();

    float y[19];
    const bool row_ok = (tid < rowsHere);
    if (row_ok) {
        float a[10], b[10];
#pragma unroll
        for (int j = 0; j < 10; ++j) {
            a[j] = sIn[tid * 10 + j];
            b[j] = sIn[TPB * 10 + tid * 10 + j];
        }
        float La[10], Lb[10];
#pragma unroll
        for (int i = 0; i < 10; ++i) {
            float l1 = 0.0f, l2 = 0.0f;
#pragma unroll
            for (int j = 0; j < 10; ++j) {
                l1 = fmaf(P[i * 10 + j], a[j], l1);
                l2 = fmaf(P[100 + i * 10 + j], b[j], l2);
            }
            l1 = fminf(fmaxf(l1, 1e-6f), 1.0f - 1e-6f);
            l2 = fminf(fmaxf(l2, 1e-6f), 1.0f - 1e-6f);
            La[i] = __logf(1.0f - l1 + 1e-12f);
            Lb[i] = __logf(1.0f - l2 + 1e-12f);
        }
        float lp[19];
#pragma unroll
        for (int k = 0; k < 19; ++k) lp[k] = 0.0f;
#pragma unroll
        for (int i = 0; i < 10; ++i) {
#pragma unroll
            for (int j = 0; j < 10; ++j) {
                lp[i + j] += fmaxf(La[i], Lb[j]);
            }
        }
        float ssum = 0.0f;
#pragma unroll
        for (int k = 0; k < 19; ++k) {
            y[k] = 1.0f - __expf(lp[k]);
            ssum += y[k];
        }
        float invs = 1.0f / (ssum + 1e-9f);
#pragma unroll
        for (int k = 0; k < 19; ++k) y[k] *= invs;
    }
    __syncthreads();  // input staging no longer needed; reuse LDS for output

    if (row_ok) {
#pragma unroll
        for (int k = 0; k < 19; ++k) sIn[tid * 19 + k] = y[k];
    }
    __syncthreads();

    // ---- store outputs (coalesced) ----
    {
        const int nflt = rowsHere * 19;
        const int nvec = nflt >> 2;
        float* og = out + (size_t)rowBase * 19;
        float4* og4 = (float4*)og;
        const float4* s4 = (const float4*)sIn;
        for (int e = tid; e < nvec; e += TPB) og4[e] = s4[e];
        for (int e = (nvec << 2) + tid; e < nflt; e += TPB) og[e] = sIn[e];
    }
}

extern "C" void kernel_launch(void* const* d_in, const int* in_sizes, int n_in,
                              void* d_out, int out_size, void* d_ws, size_t ws_size,
                              hipStream_t stream) {
    const float* p1 = (const float*)d_in[0];
    const float* p2 = (const float*)d_in[1];
    const float* W1 = (const float*)d_in[2];
    const float* W2 = (const float*)d_in[3];
    float* out = (float*)d_out;
    float* P = (float*)d_ws;  // 200 floats

    const int nrows = in_sizes[0] / 10;

    softperm_kernel<<<1, 64, 0, stream>>>(W1, W2, P);
    const int blocks = (nrows + TPB - 1) / TPB;
    bacon_main<<<blocks, TPB, 0, stream>>>(p1, p2, P, out, nrows);
}

// Round 2
// 81.150 us; speedup vs baseline: 1.0337x; 1.0337x over previous
//
#include <hip/hip_runtime.h>

#define TPB 256

// Kernel A: compute soft permutations P1, P2 (each 10x10) into d_ws.
// P layout: P[0..99] = soft_perm(W1) row-major, P[100..199] = soft_perm(W2).
__global__ void softperm_kernel(const float* __restrict__ W1,
                                const float* __restrict__ W2,
                                float* __restrict__ P) {
    int t = threadIdx.x;
    if (t >= 20) return;
    const float* W = (t < 10) ? W1 : W2;
    int r = (t < 10) ? t : (t - 10);
    float w[10];
    float lo = 1e30f, hi = -1e30f;
#pragma unroll
    for (int j = 0; j < 10; ++j) {
        w[j] = W[r * 10 + j];
        lo = fminf(lo, w[j]);
        hi = fmaxf(hi, w[j]);
    }
    float inv = 1.0f / (hi - lo + 1e-8f);
    float s = 0.0f;
#pragma unroll
    for (int j = 0; j < 10; ++j) { w[j] = (w[j] - lo) * inv; s += w[j]; }
    float invs = 1.0f / (s + 1e-8f);
#pragma unroll
    for (int j = 0; j < 10; ++j) P[t * 10 + j] = w[j] * invs;
}

// Kernel B: main. One thread per row.
//  - Stage 256 rows of p1/p2 into LDS via coalesced float4 loads.
//  - l1 = P1 @ p1row, l2 = P2 @ p2row; P via uniform (scalar) loads.
//  - NO transcendentals: exp(sum log(1-s)) == product(1-s), and
//    1-min(a,b) == max(1-a,1-b), so y_k = 1 - prod_{i+j=k} max(q_i, r_j)
//    with q_i = 1-clip(l1_i)+1e-12, r_j = 1-clip(l2_j)+1e-12.
//  - Stage 19 outputs/row in LDS, coalesced float4 store.
__global__ __launch_bounds__(TPB) void bacon_main(
    const float* __restrict__ p1, const float* __restrict__ p2,
    const float* __restrict__ P, float* __restrict__ out, int nrows) {
    // 2*256*10 floats for input staging = 20480 B; reused for output
    // staging (256*19 = 4864 floats <= 5120).
    __shared__ __align__(16) float sIn[2 * TPB * 10];

    const int tid = threadIdx.x;
    const int rowBase = blockIdx.x * TPB;
    int rowsHere = nrows - rowBase;
    if (rowsHere > TPB) rowsHere = TPB;

    // ---- stage inputs (coalesced) ----
    {
        const int nflt = rowsHere * 10;
        const int nvec = nflt >> 2;
        const float4* g1 = (const float4*)(p1 + (size_t)rowBase * 10);
        const float4* g2 = (const float4*)(p2 + (size_t)rowBase * 10);
        float4* s1 = (float4*)sIn;
        float4* s2 = (float4*)(sIn + TPB * 10);
        for (int e = tid; e < nvec; e += TPB) {
            s1[e] = g1[e];
            s2[e] = g2[e];
        }
        for (int e = (nvec << 2) + tid; e < nflt; e += TPB) {
            sIn[e] = p1[(size_t)rowBase * 10 + e];
            sIn[TPB * 10 + e] = p2[(size_t)rowBase * 10 + e];
        }
    }
    __syncthreads();

    float y[19];
    const bool row_ok = (tid < rowsHere);
    if (row_ok) {
        float a[10], b[10];
#pragma unroll
        for (int j = 0; j < 10; ++j) {
            a[j] = sIn[tid * 10 + j];
            b[j] = sIn[TPB * 10 + tid * 10 + j];
        }
        // q_i = 1 - clip(l1_i) + 1e-12, r_j likewise (all in [~1e-6, 1-1e-6])
        float q[10], r[10];
#pragma unroll
        for (int i = 0; i < 10; ++i) {
            float l1 = 0.0f, l2 = 0.0f;
#pragma unroll
            for (int j = 0; j < 10; ++j) {
                l1 = fmaf(P[i * 10 + j], a[j], l1);
                l2 = fmaf(P[100 + i * 10 + j], b[j], l2);
            }
            l1 = fminf(fmaxf(l1, 1e-6f), 1.0f - 1e-6f);
            l2 = fminf(fmaxf(l2, 1e-6f), 1.0f - 1e-6f);
            q[i] = (1.0f - l1) + 1e-12f;
            r[i] = (1.0f - l2) + 1e-12f;
        }
        // pr[k] = prod_{i+j=k} max(q_i, r_j)
        float pr[19];
#pragma unroll
        for (int k = 0; k < 19; ++k) pr[k] = 1.0f;
#pragma unroll
        for (int i = 0; i < 10; ++i) {
#pragma unroll
            for (int j = 0; j < 10; ++j) {
                pr[i + j] *= fmaxf(q[i], r[j]);
            }
        }
        float ssum = 0.0f;
#pragma unroll
        for (int k = 0; k < 19; ++k) {
            y[k] = 1.0f - pr[k];
            ssum += y[k];
        }
        float invs = 1.0f / (ssum + 1e-9f);
#pragma unroll
        for (int k = 0; k < 19; ++k) y[k] *= invs;
    }
    __syncthreads();  // input staging no longer needed; reuse LDS for output

    if (row_ok) {
#pragma unroll
        for (int k = 0; k < 19; ++k) sIn[tid * 19 + k] = y[k];
    }
    __syncthreads();

    // ---- store outputs (coalesced) ----
    {
        const int nflt = rowsHere * 19;
        const int nvec = nflt >> 2;
        float* og = out + (size_t)rowBase * 19;
        float4* og4 = (float4*)og;
        const float4* s4 = (const float4*)sIn;
        for (int e = tid; e < nvec; e += TPB) og4[e] = s4[e];
        for (int e = (nvec << 2) + tid; e < nflt; e += TPB) og[e] = sIn[e];
    }
}

extern "C" void kernel_launch(void* const* d_in, const int* in_sizes, int n_in,
                              void* d_out, int out_size, void* d_ws, size_t ws_size,
                              hipStream_t stream) {
    const float* p1 = (const float*)d_in[0];
    const float* p2 = (const float*)d_in[1];
    const float* W1 = (const float*)d_in[2];
    const float* W2 = (const float*)d_in[3];
    float* out = (float*)d_out;
    float* P = (float*)d_ws;  // 200 floats

    const int nrows = in_sizes[0] / 10;

    softperm_kernel<<<1, 64, 0, stream>>>(W1, W2, P);
    const int blocks = (nrows + TPB - 1) / TPB;
    bacon_main<<<blocks, TPB, 0, stream>>>(p1, p2, P, out, nrows);
}

// Round 3
// 79.969 us; speedup vs baseline: 1.0489x; 1.0148x over previous
//
#include <hip/hip_runtime.h>

#define TPB 256

// Single fused kernel.
//  - soft-perm algebra: row normalization invd=1/(hi-lo+1e-8) cancels between
//    numerator and denominator of l_i, leaving per-row constants
//      lo_i,  R_i = 1/((sumW_i - 10*lo_i) + 1e-8*((hi_i - lo_i) + 1e-8))
//    so   l_i = (dot(Wrow_i, x) - lo_i * sum(x)) * R_i    (exact same value).
//    Lanes 0..19 compute the 40 constants once per block -> LDS broadcast.
//  - dot products read raw W1/W2 at unroll-constant offsets -> compiler emits
//    uniform s_load; v_fmac with SGPR operand (no LDS, no VMEM per-FMA).
//  - no transcendentals: y_k = 1 - prod_{i+j=k} max(q_i, r_j),
//    q_i = 1-clip(l1_i)+1e-12, r_j = 1-clip(l2_j)+1e-12.
//  - inputs staged block-wide via coalesced float4 loads; outputs staged via
//    LDS and stored as coalesced float4.
__global__ __launch_bounds__(TPB) void bacon_fused(
    const float* __restrict__ p1, const float* __restrict__ p2,
    const float* __restrict__ W1, const float* __restrict__ W2,
    float* __restrict__ out, int nrows) {
    // input staging: 2*256*10 floats = 20480 B; reused for output staging
    // (256*19 = 4864 floats <= 5120).
    __shared__ __align__(16) float sIn[2 * TPB * 10];
    // row constants: [0..9]=lo1, [10..19]=R1, [20..29]=lo2, [30..39]=R2
    __shared__ float sC[40];

    const int tid = threadIdx.x;
    const int rowBase = blockIdx.x * TPB;
    int rowsHere = nrows - rowBase;
    if (rowsHere > TPB) rowsHere = TPB;

    // ---- stage inputs (coalesced) ----
    {
        const int nflt = rowsHere * 10;
        const int nvec = nflt >> 2;
        const float4* g1 = (const float4*)(p1 + (size_t)rowBase * 10);
        const float4* g2 = (const float4*)(p2 + (size_t)rowBase * 10);
        float4* s1 = (float4*)sIn;
        float4* s2 = (float4*)(sIn + TPB * 10);
        for (int e = tid; e < nvec; e += TPB) {
            s1[e] = g1[e];
            s2[e] = g2[e];
        }
        for (int e = (nvec << 2) + tid; e < nflt; e += TPB) {
            sIn[e] = p1[(size_t)rowBase * 10 + e];
            sIn[TPB * 10 + e] = p2[(size_t)rowBase * 10 + e];
        }
    }

    // ---- lanes 0..19: per-row soft-perm constants ----
    if (tid < 20) {
        const float* W = (tid < 10) ? W1 : W2;
        const int r = (tid < 10) ? tid : (tid - 10);
        float lo = 1e30f, hi = -1e30f, sw = 0.0f;
#pragma unroll
        for (int j = 0; j < 10; ++j) {
            float w = W[r * 10 + j];
            lo = fminf(lo, w);
            hi = fmaxf(hi, w);
            sw += w;
        }
        float R = 1.0f / ((sw - 10.0f * lo) + 1e-8f * ((hi - lo) + 1e-8f));
        const int base = (tid < 10) ? 0 : 20;
        sC[base + r] = lo;
        sC[base + 10 + r] = R;
    }
    __syncthreads();

    float y[19];
    const bool row_ok = (tid < rowsHere);
    if (row_ok) {
        float a[10], b[10];
        float sa = 0.0f, sb = 0.0f;
#pragma unroll
        for (int j = 0; j < 10; ++j) {
            a[j] = sIn[tid * 10 + j];
            b[j] = sIn[TPB * 10 + tid * 10 + j];
            sa += a[j];
            sb += b[j];
        }
        float q[10], r[10];
#pragma unroll
        for (int i = 0; i < 10; ++i) {
            float d1 = 0.0f, d2 = 0.0f;
#pragma unroll
            for (int j = 0; j < 10; ++j) {
                d1 = fmaf(W1[i * 10 + j], a[j], d1);  // s_load'd uniform W
                d2 = fmaf(W2[i * 10 + j], b[j], d2);
            }
            float l1 = (d1 - sC[i] * sa) * sC[10 + i];
            float l2 = (d2 - sC[20 + i] * sb) * sC[30 + i];
            l1 = fminf(fmaxf(l1, 1e-6f), 1.0f - 1e-6f);
            l2 = fminf(fmaxf(l2, 1e-6f), 1.0f - 1e-6f);
            q[i] = (1.0f - l1) + 1e-12f;
            r[i] = (1.0f - l2) + 1e-12f;
        }
        // pr[k] = prod_{i+j=k} max(q_i, r_j)
        float pr[19];
#pragma unroll
        for (int k = 0; k < 19; ++k) pr[k] = 1.0f;
#pragma unroll
        for (int i = 0; i < 10; ++i) {
#pragma unroll
            for (int j = 0; j < 10; ++j) {
                pr[i + j] *= fmaxf(q[i], r[j]);
            }
        }
        float ssum = 0.0f;
#pragma unroll
        for (int k = 0; k < 19; ++k) {
            y[k] = 1.0f - pr[k];
            ssum += y[k];
        }
        float invs = 1.0f / (ssum + 1e-9f);
#pragma unroll
        for (int k = 0; k < 19; ++k) y[k] *= invs;
    }
    __syncthreads();  // done reading sIn; reuse it for output staging

    if (row_ok) {
#pragma unroll
        for (int k = 0; k < 19; ++k) sIn[tid * 19 + k] = y[k];
    }
    __syncthreads();

    // ---- store outputs (coalesced) ----
    {
        const int nflt = rowsHere * 19;
        const int nvec = nflt >> 2;
        float* og = out + (size_t)rowBase * 19;
        float4* og4 = (float4*)og;
        const float4* s4 = (const float4*)sIn;
        for (int e = tid; e < nvec; e += TPB) og4[e] = s4[e];
        for (int e = (nvec << 2) + tid; e < nflt; e += TPB) og[e] = sIn[e];
    }
}

extern "C" void kernel_launch(void* const* d_in, const int* in_sizes, int n_in,
                              void* d_out, int out_size, void* d_ws, size_t ws_size,
                              hipStream_t stream) {
    const float* p1 = (const float*)d_in[0];
    const float* p2 = (const float*)d_in[1];
    const float* W1 = (const float*)d_in[2];
    const float* W2 = (const float*)d_in[3];
    float* out = (float*)d_out;

    const int nrows = in_sizes[0] / 10;
    const int blocks = (nrows + TPB - 1) / TPB;
    bacon_fused<<<blocks, TPB, 0, stream>>>(p1, p2, W1, W2, out, nrows);
}